// Round 2
// baseline (477.439 us; speedup 1.0000x reference)
//
#include <hip/hip_runtime.h>
#include <hip/hip_bf16.h>

#define BATCH 32
#define HW    56
#define PW    58
#define PAREA (PW*PW)   /* 3364 */
#define PLANE (HW*HW)   /* 3136 */

typedef float float4v __attribute__((ext_vector_type(4)));
typedef short short8  __attribute__((ext_vector_type(8)));

__device__ __forceinline__ unsigned short f2bf(float f) {
  union { float f; unsigned u; } v; v.f = f;
  unsigned r = v.u + 0x7fffu + ((v.u >> 16) & 1u);
  return (unsigned short)(r >> 16);
}

// async 16B global -> LDS (wave-uniform LDS base + lane*16)
__device__ __forceinline__ void gl_lds16(const unsigned short* g, unsigned short* l) {
  __builtin_amdgcn_global_load_lds(
      (const __attribute__((address_space(1))) unsigned int*)(const void*)g,
      (__attribute__((address_space(3))) unsigned int*)(void*)l, 16, 0, 0);
}

// ------------- Kernel 1: fused adaptive avg+max pool + dynamic weight calc -------------
// block = (b, oc); writes Wbf[b][r][oc][ic] bf16
__global__ __launch_bounds__(256) void poolw_kernel(
    const float* __restrict__ x,
    const float* __restrict__ w1, const float* __restrict__ b1,
    const float* __restrict__ w2, const float* __restrict__ b2,
    const float* __restrict__ watt, const float* __restrict__ batt,
    unsigned short* __restrict__ Wbf) {
  __shared__ float plane[PLANE];
  __shared__ float colS[5 * 56], colM[5 * 56];
  __shared__ float s_avg[25], s_max[25], s_w1[9], s_wgt1[9];
  int blk = blockIdx.x;
  int oc = blk & 255, b = blk >> 8;
  int tid = threadIdx.x;
  const float* src = x + (size_t)(b * 256 + oc) * PLANE;
  for (int e = tid; e < PLANE; e += 256) plane[e] = src[e];
  if (tid >= 32 && tid < 41) s_w1[tid - 32] = w1[oc * 9 + (tid - 32)];
  __syncthreads();
  // column-bin partials: 280 work items (j in 0..4, r in 0..55)
  for (int e = tid; e < 280; e += 256) {
    int j = e / 56, r = e - j * 56;
    int c0 = (j * 56) / 5, c1 = ((j + 1) * 56 + 4) / 5;
    float s = 0.f, m = -1e30f;
    for (int c = c0; c < c1; ++c) {
      float v = plane[r * 56 + c];
      s += v; m = fmaxf(m, v);
    }
    colS[j * 56 + r] = s; colM[j * 56 + r] = m;
  }
  __syncthreads();
  if (tid < 25) {
    int i = tid / 5, j = tid - i * 5;
    int r0 = (i * 56) / 5, r1 = ((i + 1) * 56 + 4) / 5;
    int c0 = (j * 56) / 5, c1 = ((j + 1) * 56 + 4) / 5;
    float s = 0.f, m = -1e30f;
    for (int r = r0; r < r1; ++r) {
      s += colS[j * 56 + r];
      m = fmaxf(m, colM[j * 56 + r]);
    }
    s_avg[tid] = s / (float)((r1 - r0) * (c1 - c0));
    s_max[tid] = m;
  }
  __syncthreads();
  if (tid < 9) {
    int ky = tid / 3, kx = tid % 3;
    float acc = b1[oc];
    for (int u = 0; u < 3; ++u)
      for (int v = 0; v < 3; ++v)
        acc += s_avg[(ky + u) * 5 + kx + v] * s_w1[u * 3 + v];
    s_wgt1[tid] = fmaxf(acc, 0.f);
  }
  __syncthreads();
  int ic = tid;
  size_t g = (size_t)oc * 256 + ic;
  float wa[9];
#pragma unroll
  for (int r = 0; r < 9; ++r) wa[r] = watt[g * 9 + r];
  float ba = batt[g], w2v = w2[g], b2v = b2[g];
#pragma unroll
  for (int r = 0; r < 9; ++r) {
    int ky = r / 3, kx = r % 3;
    float s = ba;
#pragma unroll
    for (int u = 0; u < 3; ++u)
#pragma unroll
      for (int v = 0; v < 3; ++v)
        s += s_max[(ky + u) * 5 + kx + v] * wa[u * 3 + v];
    float att = 1.f / (1.f + __expf(-s));
    float wv = (s_wgt1[r] * w2v + b2v) * att;
    Wbf[(((size_t)b * 9 + r) * 256 + oc) * 256 + ic] = f2bf(wv);
  }
}

// ------------- Kernel 2a: zero padded border of xp -------------
__global__ __launch_bounds__(256) void border_kernel(unsigned short* __restrict__ xp) {
  int bid = blockIdx.x;  // 32 * 228
  int b = bid / 228, bi = bid % 228;
  int pos;
  if (bi < 58)       pos = bi;
  else if (bi < 116) pos = 57 * PW + (bi - 58);
  else if (bi < 172) pos = (bi - 116 + 1) * PW;
  else               pos = (bi - 172 + 1) * PW + 57;
  xp[((size_t)b * PAREA + pos) * 256 + threadIdx.x] = 0;
}

// ------------- Kernel 2b: x fp32 [b][ic][y][x] -> xp bf16 [b][pos][ic] -------------
__global__ __launch_bounds__(256) void xprep_kernel(const float* __restrict__ x,
                                                    unsigned short* __restrict__ xp) {
  int bid = blockIdx.x;
  int y = bid % 56; int t2 = bid / 56; int icb = t2 & 3; int b = t2 >> 2;
  __shared__ float tr[56][65];
  for (int e = threadIdx.x; e < 64 * 14; e += 256) {
    int icl = e / 14, q = e - icl * 14;
    const float* sp = x + ((size_t)(b * 256 + icb * 64 + icl)) * PLANE + y * HW + q * 4;
    float4 v = *(const float4*)sp;
    tr[q * 4 + 0][icl] = v.x;
    tr[q * 4 + 1][icl] = v.y;
    tr[q * 4 + 2][icl] = v.z;
    tr[q * 4 + 3][icl] = v.w;
  }
  __syncthreads();
  for (int e = threadIdx.x; e < 448; e += 256) {
    int col = e >> 3, c8 = e & 7;
    short8 v;
#pragma unroll
    for (int k = 0; k < 8; ++k) v[k] = (short)f2bf(tr[col][c8 * 8 + k]);
    size_t dst = ((size_t)b * PAREA + (size_t)(y + 1) * PW + (col + 1)) * 256 + icb * 64 + c8 * 8;
    *(short8*)&xp[dst] = v;
  }
}

// ------------- Kernel 3: dynamic conv via MFMA -------------
// block: 128 oc x (4 rows x 56) pixels. bid: g = bid & 63 (b*2+ocb), rt = bid >> 6.
// Same-(b,ocb) blocks are 64 apart -> same XCD under round-robin -> Wbf L2-resident.
__global__ __launch_bounds__(256, 2) void conv_kernel(
    const unsigned short* __restrict__ xp,
    const unsigned short* __restrict__ Wbf,
    float* __restrict__ out) {
  // chunk-major LDS layouts (16B chunks) -> bank-balanced per 32-lane phase
  __shared__ __align__(16) unsigned short bpl[8 * 348 * 8];      // [ic8][pos][8]  44.5 KB
  __shared__ __align__(16) unsigned short apl[2][8 * 128 * 8];   // [buf][ic8][oc][8] 16 KB ea

  int bid = blockIdx.x;
  int g = bid & 63, rt = bid >> 6;
  int b = g >> 1, ocb = g & 1;
  int y0 = rt * 4;
  int tid = threadIdx.x;
  int lane = tid & 63, w = tid >> 6;
  int mw = w & 1, nw = w >> 1;
  int quad = lane >> 4, l16 = lane & 15;

  int basepos[7];
#pragma unroll
  for (int nt = 0; nt < 7; ++nt) {
    int n = nw * 112 + nt * 16 + l16;
    basepos[nt] = (n / 56) * PW + (n % 56);
  }
  int mrow[4];
#pragma unroll
  for (int mt = 0; mt < 4; ++mt) mrow[mt] = mw * 64 + mt * 16 + l16;

  float4v acc[4][7];
#pragma unroll
  for (int mt = 0; mt < 4; ++mt)
#pragma unroll
    for (int nt = 0; nt < 7; ++nt)
      acc[mt][nt] = (float4v){0.f, 0.f, 0.f, 0.f};

  const size_t xbase = ((size_t)b * PAREA + (size_t)y0 * PW) * 256;

  for (int icb = 0; icb < 4; ++icb) {   // 64-wide ic chunks
    __syncthreads();  // WAR: previous iter's bpl/apl reads complete
    // --- stage B plane: 2784 chunks of 16B, wave w owns ic-subchunks {2w,2w+1}
    {
      const unsigned short* xsrc = xp + xbase + (size_t)icb * 64;
#pragma unroll
      for (int it = 0; it < 11; ++it) {
        int el = it * 64 + lane;           // 0..695
        int cc = (el >= 348) ? 1 : 0;
        int c = 2 * w + cc;
        int p = el - cc * 348;
        unsigned short* ldst = &bpl[((size_t)w * 696 + it * 64) * 8];  // uniform
        if (el < 696)
          gl_lds16(xsrc + (size_t)p * 256 + c * 8, ldst);
      }
    }
    // --- stage A tile for r=0 into apl[0]: 1024 chunks
    {
      size_t wb = (((size_t)b * 9 + 0) * 256 + ocb * 128) * 256 + (size_t)icb * 64;
#pragma unroll
      for (int it = 0; it < 4; ++it) {
        int e = w * 256 + it * 64 + lane;
        int c = e >> 7, oc = e & 127;
        unsigned short* ldst = &apl[0][((size_t)w * 256 + it * 64) * 8];  // uniform
        gl_lds16(Wbf + wb + (size_t)oc * 256 + c * 8, ldst);
      }
    }
    __syncthreads();  // drain async loads -> bpl + apl[0] ready

    for (int r = 0; r < 9; ++r) {
      int buf = r & 1;
      if (r < 8) {   // async prefetch next tap's A tile into apl[buf^1]
        size_t wb = (((size_t)b * 9 + (r + 1)) * 256 + ocb * 128) * 256 + (size_t)icb * 64;
#pragma unroll
        for (int it = 0; it < 4; ++it) {
          int e = w * 256 + it * 64 + lane;
          int c = e >> 7, oc = e & 127;
          unsigned short* ldst = &apl[buf ^ 1][((size_t)w * 256 + it * 64) * 8];
          gl_lds16(Wbf + wb + (size_t)oc * 256 + c * 8, ldst);
        }
      }
      int ky = r / 3, kx = r - ky * 3;
      int dpos = ky * PW + kx;
#pragma unroll
      for (int h = 0; h < 2; ++h) {
        int hq = h * 4 + quad;
        short8 bfrag[7];
#pragma unroll
        for (int nt = 0; nt < 7; ++nt)
          bfrag[nt] = *(const short8*)&bpl[((size_t)hq * 348 + basepos[nt] + dpos) * 8];
#pragma unroll
        for (int mt = 0; mt < 4; ++mt) {
          short8 afrag = *(const short8*)&apl[buf][((size_t)hq * 128 + mrow[mt]) * 8];
#pragma unroll
          for (int nt = 0; nt < 7; ++nt)
            acc[mt][nt] = __builtin_amdgcn_mfma_f32_16x16x32_bf16(afrag, bfrag[nt], acc[mt][nt], 0, 0, 0);
        }
      }
      __syncthreads();  // prefetch visible; apl[buf] reads done before it's re-written
    }
  }

  // epilogue: D row = quad*4+reg (m/oc), col = l16 (n/pixel)
#pragma unroll
  for (int mt = 0; mt < 4; ++mt) {
    int m = ocb * 128 + mw * 64 + mt * 16 + quad * 4;
#pragma unroll
    for (int nt = 0; nt < 7; ++nt) {
      int n = nw * 112 + nt * 16 + l16;
      int yy = y0 + n / 56, xx = n % 56;
      size_t o = (((size_t)b * 256 + m) * 56 + yy) * 56 + xx;
#pragma unroll
      for (int reg = 0; reg < 4; ++reg)
        out[o + (size_t)reg * PLANE] = acc[mt][nt][reg];
    }
  }
}

extern "C" void kernel_launch(void* const* d_in, const int* in_sizes, int n_in,
                              void* d_out, int out_size, void* d_ws, size_t ws_size,
                              hipStream_t stream) {
  const float* x    = (const float*)d_in[0];
  const float* w1   = (const float*)d_in[1];
  const float* b1   = (const float*)d_in[2];
  const float* w2   = (const float*)d_in[3];
  const float* b2   = (const float*)d_in[4];
  const float* watt = (const float*)d_in[5];
  const float* batt = (const float*)d_in[6];
  float* out = (float*)d_out;

  unsigned short* Wbf = (unsigned short*)d_ws;                 // 32*9*256*256 bf16
  unsigned short* xp  = Wbf + (size_t)32 * 9 * 256 * 256;      // 32*3364*256 bf16

  poolw_kernel<<<BATCH * 256, 256, 0, stream>>>(x, w1, b1, w2, b2, watt, batt, Wbf);
  border_kernel<<<BATCH * 228, 256, 0, stream>>>(xp);
  xprep_kernel<<<BATCH * 4 * 56, 256, 0, stream>>>(x, xp);
  conv_kernel<<<64 * 14, 256, 0, stream>>>(xp, Wbf, out);
}